// Round 1
// baseline (630.235 us; speedup 1.0000x reference)
//
#include <hip/hip_runtime.h>

typedef short bf16x8 __attribute__((ext_vector_type(8)));
typedef float f32x4 __attribute__((ext_vector_type(4)));

#define B_ 32
#define T_ 2048
#define C_ 1024
#define H_ 64

__device__ __forceinline__ ushort f2bf(float f) {
  union { float f; unsigned u; } v; v.f = f;
  unsigned u = v.u;
  return (ushort)((u + 0x7FFFu + ((u >> 16) & 1u)) >> 16);
}

// Wt[n][c], n = mat*64 + h, mat: 0=Wk, 1=Wq (scaled by 1/8*log2e), 2=Wv
__global__ __launch_bounds__(256) void wconv_kernel(
    const float* __restrict__ Wk, const float* __restrict__ Wq,
    const float* __restrict__ Wv, ushort* __restrict__ Wt) {
  int idx = blockIdx.x * 256 + threadIdx.x;
  if (idx >= 3 * 64 * C_) return;
  int n = idx >> 10, c = idx & 1023;
  int mat = n >> 6, h = n & 63;
  const float* W = (mat == 0) ? Wk : (mat == 1 ? Wq : Wv);
  float v = W[c * 64 + h];
  if (mat == 1) v *= 0.18033688011112042f;  // 8^-1 * log2(e)
  Wt[idx] = f2bf(v);
}

// QKV projection: each wave -> 16 rows x 192 cols via 12 accumulators.
__global__ __launch_bounds__(256) void qkv_kernel(
    const float* __restrict__ x, const ushort* __restrict__ Wt,
    ushort* __restrict__ Kb, ushort* __restrict__ Qb, ushort* __restrict__ Vb) {
  int tid = threadIdx.x;
  int wave = tid >> 6, lane = tid & 63, quad = lane >> 4, l16 = lane & 15;
  int row = blockIdx.x * 64 + wave * 16 + l16;
  const float* xr = x + (size_t)row * C_;
  f32x4 acc[12];
#pragma unroll
  for (int i = 0; i < 12; ++i) acc[i] = (f32x4){0.f, 0.f, 0.f, 0.f};

  for (int k0 = 0; k0 < C_; k0 += 32) {
    const float4* xp = (const float4*)(xr + k0 + quad * 8);
    float4 a0 = xp[0], a1 = xp[1];
    bf16x8 af;
    af[0] = (short)f2bf(a0.x); af[1] = (short)f2bf(a0.y);
    af[2] = (short)f2bf(a0.z); af[3] = (short)f2bf(a0.w);
    af[4] = (short)f2bf(a1.x); af[5] = (short)f2bf(a1.y);
    af[6] = (short)f2bf(a1.z); af[7] = (short)f2bf(a1.w);
#pragma unroll
    for (int nt = 0; nt < 12; ++nt) {
      bf16x8 bf = *(const bf16x8*)(Wt + (size_t)(nt * 16 + l16) * C_ + k0 + quad * 8);
      acc[nt] = __builtin_amdgcn_mfma_f32_16x16x32_bf16(af, bf, acc[nt], 0, 0, 0);
    }
  }
  // C/D layout: col = lane&15, row = quad*4 + reg
  int orow = blockIdx.x * 64 + wave * 16 + quad * 4;
#pragma unroll
  for (int nt = 0; nt < 12; ++nt) {
    int mat = nt >> 2;
    int h = (nt & 3) * 16 + l16;
    ushort* dst = (mat == 0) ? Kb : (mat == 1 ? Qb : Vb);
#pragma unroll
    for (int r = 0; r < 4; ++r)
      dst[(size_t)(orow + r) * H_ + h] = f2bf(acc[nt][r]);
  }
}

// Flash attention: Q-tile 64 (4 waves x 16 rows), KV-tile 64, causal.
__global__ __launch_bounds__(256) void attn_kernel(
    const ushort* __restrict__ Qb, const ushort* __restrict__ Kb,
    const ushort* __restrict__ Vb, float* __restrict__ out) {
  __shared__ ushort Ks[64 * 72];  // K[j][h], pad 72 -> free 2-way
  __shared__ ushort Vt[64 * 72];  // V^T[h][j]
  __shared__ ushort Pl[64 * 72];  // P[q][j] per wave region

  int tid = threadIdx.x;
  int wave = tid >> 6, lane = tid & 63, quad = lane >> 4, l16 = lane & 15;
  int qb = blockIdx.x, batch = blockIdx.y;
  int q0 = qb * 64;
  size_t base = (size_t)batch * T_ * H_;

  // Q A-frags: A[m=lane&15][k=quad*8+j], k-halves 0..31 / 32..63
  const ushort* qrow = Qb + base + (size_t)(q0 + wave * 16 + l16) * H_;
  bf16x8 qf0 = *(const bf16x8*)(qrow + quad * 8);
  bf16x8 qf1 = *(const bf16x8*)(qrow + 32 + quad * 8);

  f32x4 o[4];
#pragma unroll
  for (int i = 0; i < 4; ++i) o[i] = (f32x4){0.f, 0.f, 0.f, 0.f};
  float m_i[4], l_i[4];
#pragma unroll
  for (int r = 0; r < 4; ++r) { m_i[r] = -1e30f; l_i[r] = 0.f; }

  int sr = tid >> 2;   // staging row 0..63
  int sc = tid & 3;    // staging 16-elem segment 0..3

  for (int jb = 0; jb <= qb; ++jb) {
    int j0 = jb * 64;
    __syncthreads();  // protect previous iter's LDS reads
    // stage K tile
    const ushort* kg = Kb + base + (size_t)(j0 + sr) * H_ + sc * 16;
    *(bf16x8*)(&Ks[sr * 72 + sc * 16]) = *(const bf16x8*)(kg);
    *(bf16x8*)(&Ks[sr * 72 + sc * 16 + 8]) = *(const bf16x8*)(kg + 8);
    // stage V transposed
    const ushort* vg = Vb + base + (size_t)(j0 + sr) * H_ + sc * 16;
    bf16x8 v0 = *(const bf16x8*)(vg);
    bf16x8 v1 = *(const bf16x8*)(vg + 8);
#pragma unroll
    for (int i = 0; i < 8; ++i) {
      Vt[(sc * 16 + i) * 72 + sr] = (ushort)v0[i];
      Vt[(sc * 16 + 8 + i) * 72 + sr] = (ushort)v1[i];
    }
    __syncthreads();

    // S = Q K^T : B-frag of K^T = K read as A-layout from Ks
    f32x4 sv[4];
#pragma unroll
    for (int nt = 0; nt < 4; ++nt) {
      bf16x8 kf0 = *(const bf16x8*)(&Ks[(nt * 16 + l16) * 72 + quad * 8]);
      bf16x8 kf1 = *(const bf16x8*)(&Ks[(nt * 16 + l16) * 72 + 32 + quad * 8]);
      f32x4 z = (f32x4){0.f, 0.f, 0.f, 0.f};
      z = __builtin_amdgcn_mfma_f32_16x16x32_bf16(qf0, kf0, z, 0, 0, 0);
      z = __builtin_amdgcn_mfma_f32_16x16x32_bf16(qf1, kf1, z, 0, 0, 0);
      sv[nt] = z;
    }

    // causal mask on the diagonal block
    if (jb == qb) {
      int rowg = q0 + wave * 16 + quad * 4;
#pragma unroll
      for (int nt = 0; nt < 4; ++nt) {
        int col = j0 + nt * 16 + l16;
#pragma unroll
        for (int rr = 0; rr < 4; ++rr)
          if (col > rowg + rr) sv[nt][rr] = -1e30f;
      }
    }

    // online softmax (base-2 domain; scale folded into Wq)
    float alpha[4];
#pragma unroll
    for (int rr = 0; rr < 4; ++rr) {
      float v = fmaxf(fmaxf(sv[0][rr], sv[1][rr]), fmaxf(sv[2][rr], sv[3][rr]));
      v = fmaxf(v, __shfl_xor(v, 1));
      v = fmaxf(v, __shfl_xor(v, 2));
      v = fmaxf(v, __shfl_xor(v, 4));
      v = fmaxf(v, __shfl_xor(v, 8));
      float mn = fmaxf(m_i[rr], v);
      alpha[rr] = exp2f(m_i[rr] - mn);
      m_i[rr] = mn;
    }
    float p[4][4];
    float rsum[4] = {0.f, 0.f, 0.f, 0.f};
#pragma unroll
    for (int nt = 0; nt < 4; ++nt)
#pragma unroll
      for (int rr = 0; rr < 4; ++rr) {
        p[nt][rr] = exp2f(sv[nt][rr] - m_i[rr]);
        rsum[rr] += p[nt][rr];
      }
#pragma unroll
    for (int rr = 0; rr < 4; ++rr) l_i[rr] = alpha[rr] * l_i[rr] + rsum[rr];
#pragma unroll
    for (int ht = 0; ht < 4; ++ht)
#pragma unroll
      for (int rr = 0; rr < 4; ++rr) o[ht][rr] *= alpha[rr];

    // P: C-layout -> LDS -> A-layout (m120 pattern)
    int prow = wave * 16 + quad * 4;
#pragma unroll
    for (int nt = 0; nt < 4; ++nt)
#pragma unroll
      for (int rr = 0; rr < 4; ++rr)
        Pl[(prow + rr) * 72 + nt * 16 + l16] = f2bf(p[nt][rr]);
    __syncthreads();

    bf16x8 pf0 = *(const bf16x8*)(&Pl[(wave * 16 + l16) * 72 + quad * 8]);
    bf16x8 pf1 = *(const bf16x8*)(&Pl[(wave * 16 + l16) * 72 + 32 + quad * 8]);
#pragma unroll
    for (int ht = 0; ht < 4; ++ht) {
      bf16x8 vf0 = *(const bf16x8*)(&Vt[(ht * 16 + l16) * 72 + quad * 8]);
      bf16x8 vf1 = *(const bf16x8*)(&Vt[(ht * 16 + l16) * 72 + 32 + quad * 8]);
      o[ht] = __builtin_amdgcn_mfma_f32_16x16x32_bf16(pf0, vf0, o[ht], 0, 0, 0);
      o[ht] = __builtin_amdgcn_mfma_f32_16x16x32_bf16(pf1, vf1, o[ht], 0, 0, 0);
    }
  }

  // finalize: reduce per-lane partial l over the quad's 16 lanes
#pragma unroll
  for (int rr = 0; rr < 4; ++rr) {
    float v = l_i[rr];
    v += __shfl_xor(v, 1);
    v += __shfl_xor(v, 2);
    v += __shfl_xor(v, 4);
    v += __shfl_xor(v, 8);
    l_i[rr] = v;
  }
  int orow = q0 + wave * 16 + quad * 4;
#pragma unroll
  for (int ht = 0; ht < 4; ++ht)
#pragma unroll
    for (int rr = 0; rr < 4; ++rr)
      out[base + (size_t)(orow + rr) * H_ + ht * 16 + l16] = o[ht][rr] / l_i[rr];
}

extern "C" void kernel_launch(void* const* d_in, const int* in_sizes, int n_in,
                              void* d_out, int out_size, void* d_ws, size_t ws_size,
                              hipStream_t stream) {
  const float* x  = (const float*)d_in[0];
  const float* Wk = (const float*)d_in[1];
  const float* Wq = (const float*)d_in[2];
  const float* Wv = (const float*)d_in[3];
  float* out = (float*)d_out;

  // workspace layout
  ushort* Wt = (ushort*)d_ws;                              // 384 KB
  ushort* Kb = (ushort*)((char*)d_ws + (1 << 19));         // 8 MB each
  ushort* Qb = Kb + (size_t)B_ * T_ * H_;
  ushort* Vb = Qb + (size_t)B_ * T_ * H_;

  hipLaunchKernelGGL(wconv_kernel, dim3(768), dim3(256), 0, stream, Wk, Wq, Wv, Wt);
  hipLaunchKernelGGL(qkv_kernel, dim3(1024), dim3(256), 0, stream, x, Wt, Kb, Qb, Vb);
  hipLaunchKernelGGL(attn_kernel, dim3(32, 32), dim3(256), 0, stream, Qb, Kb, Vb, out);
}

// Round 2
// 514.555 us; speedup vs baseline: 1.2248x; 1.2248x over previous
//
#include <hip/hip_runtime.h>

typedef short bf16x8 __attribute__((ext_vector_type(8)));
typedef float f32x4 __attribute__((ext_vector_type(4)));

#define B_ 32
#define T_ 2048
#define C_ 1024
#define H_ 64

__device__ __forceinline__ ushort f2bf(float f) {
  union { float f; unsigned u; } v; v.f = f;
  unsigned u = v.u;
  return (ushort)((u + 0x7FFFu + ((u >> 16) & 1u)) >> 16);
}

__device__ __forceinline__ void async_copy16(void* lds, const void* g) {
  __builtin_amdgcn_global_load_lds(
      (const __attribute__((address_space(1))) unsigned int*)g,
      (__attribute__((address_space(3))) unsigned int*)lds, 16, 0, 0);
}

// Wt[n][c], n = mat*64 + h, mat: 0=Wk, 1=Wq (scaled by 1/8*log2e), 2=Wv
__global__ __launch_bounds__(256) void wconv_kernel(
    const float* __restrict__ Wk, const float* __restrict__ Wq,
    const float* __restrict__ Wv, ushort* __restrict__ Wt) {
  int idx = blockIdx.x * 256 + threadIdx.x;
  if (idx >= 3 * 64 * C_) return;
  int n = idx >> 10, c = idx & 1023;
  int mat = n >> 6, h = n & 63;
  const float* W = (mat == 0) ? Wk : (mat == 1 ? Wq : Wv);
  float v = W[c * 64 + h];
  if (mat == 1) v *= 0.18033688011112042f;  // 8^-1 * log2(e)
  Wt[idx] = f2bf(v);
}

// QKV projection, m97-style: global_load_lds staging + XOR-swizzled LDS.
// Block: 128 rows x 192 cols, 4 waves, each wave 32 rows (2 row-tiles) x 12 col-tiles.
// V is written TRANSPOSED: Vt[b][h][t].
__global__ __launch_bounds__(256) void qkv_kernel(
    const float* __restrict__ x, const ushort* __restrict__ Wt,
    ushort* __restrict__ Kb, ushort* __restrict__ Qb, ushort* __restrict__ Vt) {
  __shared__ __align__(16) float As[128 * 64];   // 32 KB, chunk16 XOR-swizzled
  __shared__ __align__(16) ushort Bs[192 * 64];  // 24 KB, chunk8 XOR-swizzled
  int tid = threadIdx.x;
  int wave = tid >> 6, lane = tid & 63, quad = lane >> 4, l16 = lane & 15;
  int r0 = blockIdx.x * 128;

  f32x4 acc[2][12];
#pragma unroll
  for (int rt = 0; rt < 2; ++rt)
#pragma unroll
    for (int nt = 0; nt < 12; ++nt) acc[rt][nt] = (f32x4){0.f, 0.f, 0.f, 0.f};

  for (int k0 = 0; k0 < C_; k0 += 64) {
    __syncthreads();  // prior reads done before overwrite
    // stage A: 128 rows x 16 chunks (16B = 4 fp32); swizzle c' = c ^ (row&15)
#pragma unroll
    for (int i = 0; i < 8; ++i) {
      int id = tid + 256 * i;
      int arow = id >> 4, acp = id & 15;
      int ac = acp ^ (arow & 15);
      async_copy16((char*)As + id * 16,
                   x + (size_t)(r0 + arow) * C_ + k0 + ac * 4);
    }
    // stage B: 192 rows x 8 chunks (16B = 8 bf16); swizzle c' = c ^ (n&7)
#pragma unroll
    for (int i = 0; i < 6; ++i) {
      int id = tid + 256 * i;
      int bn = id >> 3, bcp = id & 7;
      int bc = bcp ^ (bn & 7);
      async_copy16((char*)Bs + id * 16,
                   Wt + (size_t)bn * C_ + k0 + bc * 8);
    }
    __syncthreads();

#pragma unroll
    for (int ks = 0; ks < 2; ++ks) {
      bf16x8 af[2];
#pragma unroll
      for (int rt = 0; rt < 2; ++rt) {
        int row = wave * 32 + rt * 16 + l16;  // row & 15 == l16
        int c0 = ks * 8 + quad * 2;
        f32x4 a0 = *(const f32x4*)(As + row * 64 + ((c0 ^ l16) << 2));
        f32x4 a1 = *(const f32x4*)(As + row * 64 + (((c0 + 1) ^ l16) << 2));
        bf16x8 t;
        t[0] = (short)f2bf(a0[0]); t[1] = (short)f2bf(a0[1]);
        t[2] = (short)f2bf(a0[2]); t[3] = (short)f2bf(a0[3]);
        t[4] = (short)f2bf(a1[0]); t[5] = (short)f2bf(a1[1]);
        t[6] = (short)f2bf(a1[2]); t[7] = (short)f2bf(a1[3]);
        af[rt] = t;
      }
#pragma unroll
      for (int nt = 0; nt < 12; ++nt) {
        int n = nt * 16 + l16;
        int cb = ks * 4 + quad;
        bf16x8 bf = *(const bf16x8*)(Bs + n * 64 + ((cb ^ (l16 & 7)) << 3));
        acc[0][nt] = __builtin_amdgcn_mfma_f32_16x16x32_bf16(af[0], bf, acc[0][nt], 0, 0, 0);
        acc[1][nt] = __builtin_amdgcn_mfma_f32_16x16x32_bf16(af[1], bf, acc[1][nt], 0, 0, 0);
      }
    }
  }

  // epilogue. C layout: col = l16, row = quad*4 + r
  int b = r0 >> 11;
#pragma unroll
  for (int rt = 0; rt < 2; ++rt) {
    int rowbase = r0 + wave * 32 + rt * 16 + quad * 4;
#pragma unroll
    for (int nt = 0; nt < 12; ++nt) {
      int mat = nt >> 2;
      int h = (nt & 3) * 16 + l16;
#pragma unroll
      for (int r = 0; r < 4; ++r) {
        ushort val = f2bf(acc[rt][nt][r]);
        int row = rowbase + r;
        if (mat == 0)      Kb[(size_t)row * H_ + h] = val;
        else if (mat == 1) Qb[(size_t)row * H_ + h] = val;
        else               Vt[(size_t)b * H_ * T_ + (size_t)h * T_ + (row & (T_ - 1))] = val;
      }
    }
  }
}

// Flash attention, barrier-free: each wave owns 32 q-rows; K/V^T/Q read
// directly from global (L2-resident per batch); P round-trips per-wave LDS.
__global__ __launch_bounds__(256) void attn_kernel(
    const ushort* __restrict__ Qb, const ushort* __restrict__ Kb,
    const ushort* __restrict__ Vt, float* __restrict__ out) {
  __shared__ __align__(16) ushort Pl[4 * 32 * 80];  // stride 80: free writes, 4-way b128 reads

  int tid = threadIdx.x;
  int wave = tid >> 6, lane = tid & 63, quad = lane >> 4, l16 = lane & 15;
  int batch = blockIdx.y;
  int q0 = blockIdx.x * 128 + wave * 32;
  const ushort* Qbase = Qb + (size_t)batch * T_ * H_;
  const ushort* Kbase = Kb + (size_t)batch * T_ * H_;
  const ushort* Vbase = Vt + (size_t)batch * H_ * T_;
  ushort* Pw = Pl + wave * 32 * 80;

  bf16x8 qf[2][2];
#pragma unroll
  for (int rt = 0; rt < 2; ++rt) {
    const ushort* qr = Qbase + (size_t)(q0 + rt * 16 + l16) * H_;
    qf[rt][0] = *(const bf16x8*)(qr + quad * 8);
    qf[rt][1] = *(const bf16x8*)(qr + 32 + quad * 8);
  }

  f32x4 o[2][4];
  float m_i[2][4], l_i[2][4];
#pragma unroll
  for (int rt = 0; rt < 2; ++rt)
#pragma unroll
    for (int i = 0; i < 4; ++i) {
      o[rt][i] = (f32x4){0.f, 0.f, 0.f, 0.f};
      m_i[rt][i] = -1e30f; l_i[rt][i] = 0.f;
    }

  int jb_last = (q0 + 31) >> 6;
  for (int jb = 0; jb <= jb_last; ++jb) {
    int j0 = jb * 64;

    // S = Q K^T
    f32x4 sv[2][4];
#pragma unroll
    for (int nt = 0; nt < 4; ++nt) {
      const ushort* kr = Kbase + (size_t)(j0 + nt * 16 + l16) * H_;
      bf16x8 kf0 = *(const bf16x8*)(kr + quad * 8);
      bf16x8 kf1 = *(const bf16x8*)(kr + 32 + quad * 8);
#pragma unroll
      for (int rt = 0; rt < 2; ++rt) {
        f32x4 z = (f32x4){0.f, 0.f, 0.f, 0.f};
        z = __builtin_amdgcn_mfma_f32_16x16x32_bf16(qf[rt][0], kf0, z, 0, 0, 0);
        z = __builtin_amdgcn_mfma_f32_16x16x32_bf16(qf[rt][1], kf1, z, 0, 0, 0);
        sv[rt][nt] = z;
      }
    }

    if (jb == jb_last) {  // causal mask on diagonal region
#pragma unroll
      for (int rt = 0; rt < 2; ++rt) {
        int rowg = q0 + rt * 16 + quad * 4;
#pragma unroll
        for (int nt = 0; nt < 4; ++nt) {
          int col = j0 + nt * 16 + l16;
#pragma unroll
          for (int rr = 0; rr < 4; ++rr)
            if (col > rowg + rr) sv[rt][nt][rr] = -1e30f;
        }
      }
    }

    // online softmax (base-2; 1/8*log2e folded into Wq)
    float alpha[2][4];
#pragma unroll
    for (int rt = 0; rt < 2; ++rt)
#pragma unroll
      for (int rr = 0; rr < 4; ++rr) {
        float v = fmaxf(fmaxf(sv[rt][0][rr], sv[rt][1][rr]),
                        fmaxf(sv[rt][2][rr], sv[rt][3][rr]));
        v = fmaxf(v, __shfl_xor(v, 1));
        v = fmaxf(v, __shfl_xor(v, 2));
        v = fmaxf(v, __shfl_xor(v, 4));
        v = fmaxf(v, __shfl_xor(v, 8));
        float mn = fmaxf(m_i[rt][rr], v);
        alpha[rt][rr] = exp2f(m_i[rt][rr] - mn);
        m_i[rt][rr] = mn;
      }

#pragma unroll
    for (int rt = 0; rt < 2; ++rt) {
      float rsum[4] = {0.f, 0.f, 0.f, 0.f};
#pragma unroll
      for (int nt = 0; nt < 4; ++nt)
#pragma unroll
        for (int rr = 0; rr < 4; ++rr) {
          float p = exp2f(sv[rt][nt][rr] - m_i[rt][rr]);
          rsum[rr] += p;
          Pw[(rt * 16 + quad * 4 + rr) * 80 + nt * 16 + l16] = f2bf(p);
        }
#pragma unroll
      for (int rr = 0; rr < 4; ++rr)
        l_i[rt][rr] = alpha[rt][rr] * l_i[rt][rr] + rsum[rr];
#pragma unroll
      for (int ht = 0; ht < 4; ++ht)
#pragma unroll
        for (int rr = 0; rr < 4; ++rr) o[rt][ht][rr] *= alpha[rt][rr];
    }

    // P (A-layout) from same-wave LDS region — no barrier needed
    bf16x8 pf[2][2];
#pragma unroll
    for (int rt = 0; rt < 2; ++rt) {
      pf[rt][0] = *(const bf16x8*)(&Pw[(rt * 16 + l16) * 80 + quad * 8]);
      pf[rt][1] = *(const bf16x8*)(&Pw[(rt * 16 + l16) * 80 + 32 + quad * 8]);
    }
#pragma unroll
    for (int ht = 0; ht < 4; ++ht) {
      const ushort* vr = Vbase + (size_t)(ht * 16 + l16) * T_ + j0;
      bf16x8 vf0 = *(const bf16x8*)(vr + quad * 8);
      bf16x8 vf1 = *(const bf16x8*)(vr + 32 + quad * 8);
#pragma unroll
      for (int rt = 0; rt < 2; ++rt) {
        o[rt][ht] = __builtin_amdgcn_mfma_f32_16x16x32_bf16(pf[rt][0], vf0, o[rt][ht], 0, 0, 0);
        o[rt][ht] = __builtin_amdgcn_mfma_f32_16x16x32_bf16(pf[rt][1], vf1, o[rt][ht], 0, 0, 0);
      }
    }
  }

  // finalize
#pragma unroll
  for (int rt = 0; rt < 2; ++rt)
#pragma unroll
    for (int rr = 0; rr < 4; ++rr) {
      float v = l_i[rt][rr];
      v += __shfl_xor(v, 1);
      v += __shfl_xor(v, 2);
      v += __shfl_xor(v, 4);
      v += __shfl_xor(v, 8);
      l_i[rt][rr] = v;
    }
#pragma unroll
  for (int rt = 0; rt < 2; ++rt) {
    int rowbase = q0 + rt * 16 + quad * 4;
#pragma unroll
    for (int ht = 0; ht < 4; ++ht)
#pragma unroll
      for (int rr = 0; rr < 4; ++rr)
        out[((size_t)batch * T_ + rowbase + rr) * H_ + ht * 16 + l16] =
            o[rt][ht][rr] / l_i[rt][rr];
  }
}

extern "C" void kernel_launch(void* const* d_in, const int* in_sizes, int n_in,
                              void* d_out, int out_size, void* d_ws, size_t ws_size,
                              hipStream_t stream) {
  const float* x  = (const float*)d_in[0];
  const float* Wk = (const float*)d_in[1];
  const float* Wq = (const float*)d_in[2];
  const float* Wv = (const float*)d_in[3];
  float* out = (float*)d_out;

  ushort* Wt = (ushort*)d_ws;                              // 384 KB
  ushort* Kb = (ushort*)((char*)d_ws + (1 << 19));         // 8 MB each
  ushort* Qb = Kb + (size_t)B_ * T_ * H_;
  ushort* Vt = Qb + (size_t)B_ * T_ * H_;                  // transposed [b][h][t]

  hipLaunchKernelGGL(wconv_kernel, dim3(768), dim3(256), 0, stream, Wk, Wq, Wv, Wt);
  hipLaunchKernelGGL(qkv_kernel, dim3(512), dim3(256), 0, stream, x, Wt, Kb, Qb, Vt);
  hipLaunchKernelGGL(attn_kernel, dim3(16, 32), dim3(256), 0, stream, Qb, Kb, Vt, out);
}